// Round 11
// baseline (60.629 us; speedup 1.0000x reference)
//
#include <hip/hip_runtime.h>
#include <hip/hip_bf16.h>

#define B_ 8
#define N_ 16384
#define S_ 1024
#define K_ 32
#define CSTEM 64
#define CPATCH 128
#define INDIM 91
#define LDH 136     // Hs row stride (bf16)
#define NQ 4        // patches per MLP block
#define AFRAG 3072  // bf16 per patch in A-frag layout: 6 frags x 64 lanes x 8

typedef __attribute__((ext_vector_type(8))) short short8v;  // 8 bf16 = 4 VGPRs
typedef __attribute__((ext_vector_type(4))) float f32x4;

static __device__ __forceinline__ unsigned short f2bf(float f) {
  union { float f; unsigned int u; } v; v.f = f;
  return (unsigned short)((v.u + 0x7FFFu + ((v.u >> 16) & 1u)) >> 16);  // RNE
}

static __device__ __forceinline__ short8v cvt8(const float4 a, const float4 b) {
  unsigned short v[8];
  v[0] = f2bf(a.x); v[1] = f2bf(a.y); v[2] = f2bf(a.z); v[3] = f2bf(a.w);
  v[4] = f2bf(b.x); v[5] = f2bf(b.y); v[6] = f2bf(b.z); v[7] = f2bf(b.w);
  return *(const short8v*)v;
}

// PE/rel fragment: cols [64+kq, 64+kq+8) of one row (R8-verified numerics).
static __device__ __forceinline__ short8v pe_frag(
    float r0, float r1, float r2, int kq)
{
  unsigned short v[8];
  #pragma unroll
  for (int j = 0; j < 8; ++j) {
    const int c = 64 + kq + j;
    float val;
    if (c < 67) {
      val = (c == 64) ? r0 : ((c == 65) ? r1 : r2);
    } else if (c < 91) {
      const int qq = c - 67, d = qq >> 3, rbit = qq & 7, band = rbit & 3;
      const float rel = (d == 0) ? r0 : ((d == 1) ? r1 : r2);
      const float ang = rel * ((float)(1 << band) * 3.14159265358979323846f);
      val = (rbit < 4) ? __sinf(ang) : __cosf(ang);
    } else {
      val = 0.f;
    }
    v[j] = f2bf(val);
  }
  return *(const short8v*)v;
}

// -------- Kernel 0: pack w1/w2 into MFMA B-fragment order (bf16) --------
__global__ __launch_bounds__(256) void pack_weights(
    const float* __restrict__ w1, const float* __restrict__ w2,
    unsigned short* __restrict__ w1p, unsigned short* __restrict__ w2p)
{
  const int id = blockIdx.x * 256 + threadIdx.x;
  if (id < 3 * 8 * 64) {                       // w1: K padded 91->96 (3 ksteps)
    const int l = id & 63, ct = (id >> 6) & 7, ks = id >> 9;
    const int col = 16 * ct + (l & 15);
    const int kb = 32 * ks + (l >> 4) * 8;
    unsigned short v[8];
    #pragma unroll
    for (int j = 0; j < 8; ++j) {
      const int k = kb + j;
      v[j] = (k < INDIM) ? f2bf(w1[k * CPATCH + col]) : (unsigned short)0;
    }
    *(short8v*)&w1p[(size_t)id * 8] = *(const short8v*)v;
  } else if (id < 3 * 8 * 64 + 4 * 8 * 64) {   // w2: 4 ksteps
    const int id2 = id - 3 * 8 * 64;
    const int l = id2 & 63, ct = (id2 >> 6) & 7, ks = id2 >> 9;
    const int col = 16 * ct + (l & 15);
    const int kb = 32 * ks + (l >> 4) * 8;
    unsigned short v[8];
    #pragma unroll
    for (int j = 0; j < 8; ++j) v[j] = f2bf(w2[(kb + j) * CPATCH + col]);
    *(short8v*)&w2p[(size_t)id2 * 8] = *(const short8v*)v;
  }
}

// component accessor for an unrolled float4 array (IDX must be compile-time)
#define FCOMP(V, IDX) (((IDX) & 3) == 0 ? (V)[(IDX) >> 2].x : \
                       ((IDX) & 3) == 1 ? (V)[(IDX) >> 2].y : \
                       ((IDX) & 3) == 2 ? (V)[(IDX) >> 2].z : (V)[(IDX) >> 2].w)

// -------- Kernel 1: ball query + A-tile gather, one wave per query --------
// Barrier-free: each wave scans (1024 pts/iter, verified f32-band+f64 math),
// pads, writes idx, then gathers its patch's 32x96 A-tile straight into
// MFMA A-fragment order in d_ws: [patch][ks(3)][rt(2)][lane(64)][8 bf16].
__global__ __launch_bounds__(256) void ball_gather_kernel(
    const float* __restrict__ xyz, const float* __restrict__ pf,
    const float* __restrict__ pc,
    unsigned short* __restrict__ agather, float* __restrict__ idx_out)
{
  const int lane = threadIdx.x & 63;
  const int w    = threadIdx.x >> 6;
  const int bs   = blockIdx.x * 4 + w;
  const int b    = bs >> 10;                   // S_ = 1024

  __shared__ int   sidx[4][K_];
  __shared__ float sxyz[4][K_][3];

  const float* __restrict__ xb  = xyz + (size_t)b * N_ * 3;
  const float* __restrict__ pfb = pf  + (size_t)b * N_ * CSTEM;
  const float cx = pc[bs * 3 + 0];
  const float cy = pc[bs * 3 + 1];
  const float cz = pc[bs * 3 + 2];
  const double rr = 0.2 * 0.2;

  int found = 0;
  for (int base = 0; base < N_; base += 1024) {
    const int i0 = base + lane * 16;           // 16 consecutive pts per lane
    float4 v[12];
    #pragma unroll
    for (int t = 0; t < 12; ++t)
      v[t] = *(const float4*)&xb[i0 * 3 + t * 4];

    unsigned mask = 0u;
    #pragma unroll
    for (int p = 0; p < 16; ++p) {
      const float X = FCOMP(v, 3 * p + 0);
      const float Y = FCOMP(v, 3 * p + 1);
      const float Z = FCOMP(v, 3 * p + 2);
      const float dxf = X - cx, dyf = Y - cy, dzf = Z - cz;
      const float d2f = fmaf(dxf, dxf, fmaf(dyf, dyf, dzf * dzf));
      bool in;
      if (fabsf(d2f - 0.04f) <= 1e-5f) {       // rare exact f64 recheck
        const double dx = (double)X - (double)cx;
        const double dy = (double)Y - (double)cy;
        const double dz = (double)Z - (double)cz;
        in = (dx * dx + dy * dy + dz * dz) <= rr;
      } else {
        in = (d2f < 0.04f);
      }
      if (in) mask |= (1u << p);
    }

    const int cnt = __popc(mask);
    int incl = cnt;                            // wave-inclusive prefix
    #pragma unroll
    for (int d = 1; d < 64; d <<= 1) {
      const int t = __shfl_up(incl, d);
      if (lane >= d) incl += t;
    }
    const int tot = __shfl(incl, 63);

    int pos = found + (incl - cnt);
    #pragma unroll
    for (int p = 0; p < 16; ++p) {             // static p: no dyn reg indexing
      if (mask & (1u << p)) {
        if (pos < K_) {
          sidx[w][pos] = i0 + p;
          sxyz[w][pos][0] = FCOMP(v, 3 * p + 0);
          sxyz[w][pos][1] = FCOMP(v, 3 * p + 1);
          sxyz[w][pos][2] = FCOMP(v, 3 * p + 2);
        }
        ++pos;
      }
    }
    found += tot;
    if (found >= K_) break;                    // wave-uniform
  }

  if (lane == 0 && found == 0) {               // none found -> index N-1
    sidx[w][0] = N_ - 1;
    sxyz[w][0][0] = xb[(N_ - 1) * 3 + 0];
    sxyz[w][0][1] = xb[(N_ - 1) * 3 + 1];
    sxyz[w][0][2] = xb[(N_ - 1) * 3 + 2];
  }
  __threadfence_block();                       // wave-local LDS drain

  if (lane < K_) {                             // pad with first found
    const int   fill = sidx[w][0];
    const float fx = sxyz[w][0][0];
    const float fy = sxyz[w][0][1];
    const float fz = sxyz[w][0][2];
    const int v = (lane < found) ? sidx[w][lane] : fill;
    if (lane >= found) {
      sidx[w][lane] = fill;
      sxyz[w][lane][0] = fx;
      sxyz[w][lane][1] = fy;
      sxyz[w][lane][2] = fz;
    }
    idx_out[(size_t)bs * K_ + lane] = (float)v;
  }
  __threadfence_block();

  // ---- Gather: write A-tile in fragment order (coalesced 1KB stores) ----
  unsigned short* __restrict__ ag = agather + (size_t)bs * AFRAG;
  const int koff = (lane >> 4) * 8;            // 0,8,16,24
  #pragma unroll
  for (int rt = 0; rt < 2; ++rt) {
    const int row = rt * 16 + (lane & 15);
    const int r = sidx[w][row];
    const float4 f0 = *(const float4*)&pfb[(size_t)r * CSTEM + koff];
    const float4 f1 = *(const float4*)&pfb[(size_t)r * CSTEM + koff + 4];
    const float4 g0 = *(const float4*)&pfb[(size_t)r * CSTEM + 32 + koff];
    const float4 g1 = *(const float4*)&pfb[(size_t)r * CSTEM + 32 + koff + 4];
    const float r0 = sxyz[w][row][0] - cx;
    const float r1 = sxyz[w][row][1] - cy;
    const float r2 = sxyz[w][row][2] - cz;
    *(short8v*)&ag[((0 * 2 + rt) * 64 + lane) * 8] = cvt8(f0, f1);
    *(short8v*)&ag[((1 * 2 + rt) * 64 + lane) * 8] = cvt8(g0, g1);
    *(short8v*)&ag[((2 * 2 + rt) * 64 + lane) * 8] = pe_frag(r0, r1, r2, koff);
  }
}

// -------- Kernel 2: pure MFMA MLP; A-frags via coalesced global loads -----
// LDS = Hs only (8.7KB). Weights register-resident. 2 barriers/patch.
__global__ __launch_bounds__(256) void patch_mlp_mfma(
    const unsigned short* __restrict__ agather,
    const unsigned short* __restrict__ w1p, const float* __restrict__ b1,
    const unsigned short* __restrict__ w2p, const float* __restrict__ b2,
    float* __restrict__ out)
{
  const int tid  = threadIdx.x;
  const int lane = tid & 63;
  const int w    = tid >> 6;
  const int bs0  = blockIdx.x * NQ;

  __shared__ __align__(16) unsigned short Hs[K_][LDH];

  short8v w1f[3][2], w2f[4][2];
  #pragma unroll
  for (int ks = 0; ks < 3; ++ks)
    #pragma unroll
    for (int t = 0; t < 2; ++t)
      w1f[ks][t] = *(const short8v*)&w1p[((size_t)(ks * 8 + 2 * w + t) * 64 + lane) * 8];
  #pragma unroll
  for (int ks = 0; ks < 4; ++ks)
    #pragma unroll
    for (int t = 0; t < 2; ++t)
      w2f[ks][t] = *(const short8v*)&w2p[((size_t)(ks * 8 + 2 * w + t) * 64 + lane) * 8];
  const float bias1[2] = { b1[32 * w + (lane & 15)], b1[32 * w + 16 + (lane & 15)] };
  const float bias2[2] = { b2[32 * w + (lane & 15)], b2[32 * w + 16 + (lane & 15)] };

  #pragma unroll
  for (int q = 0; q < NQ; ++q) {
    const unsigned short* __restrict__ ap = agather + (size_t)(bs0 + q) * AFRAG;
    // A-fragments: 6 coalesced 16B-per-lane loads
    short8v af[6];
    #pragma unroll
    for (int f = 0; f < 6; ++f)
      af[f] = *(const short8v*)&ap[((size_t)(f * 64) + lane) * 8];

    f32x4 acc[2][2] = {};
    #pragma unroll
    for (int ks = 0; ks < 3; ++ks) {
      acc[0][0] = __builtin_amdgcn_mfma_f32_16x16x32_bf16(af[ks * 2 + 0], w1f[ks][0], acc[0][0], 0, 0, 0);
      acc[0][1] = __builtin_amdgcn_mfma_f32_16x16x32_bf16(af[ks * 2 + 0], w1f[ks][1], acc[0][1], 0, 0, 0);
      acc[1][0] = __builtin_amdgcn_mfma_f32_16x16x32_bf16(af[ks * 2 + 1], w1f[ks][0], acc[1][0], 0, 0, 0);
      acc[1][1] = __builtin_amdgcn_mfma_f32_16x16x32_bf16(af[ks * 2 + 1], w1f[ks][1], acc[1][1], 0, 0, 0);
    }
    #pragma unroll
    for (int rt = 0; rt < 2; ++rt)
      #pragma unroll
      for (int t = 0; t < 2; ++t)
        #pragma unroll
        for (int reg = 0; reg < 4; ++reg) {
          const float h = fmaxf(acc[rt][t][reg] + bias1[t], 0.f);
          const int row = 16 * rt + (lane >> 4) * 4 + reg;
          const int col = 32 * w + 16 * t + (lane & 15);
          Hs[row][col] = f2bf(h);
        }
    __syncthreads();

    f32x4 acc2[2][2] = {};
    #pragma unroll
    for (int ks = 0; ks < 4; ++ks) {
      const int k0 = ks * 32 + (lane >> 4) * 8;
      const short8v a0 = *(const short8v*)&Hs[(lane & 15)][k0];
      const short8v a1 = *(const short8v*)&Hs[16 + (lane & 15)][k0];
      acc2[0][0] = __builtin_amdgcn_mfma_f32_16x16x32_bf16(a0, w2f[ks][0], acc2[0][0], 0, 0, 0);
      acc2[0][1] = __builtin_amdgcn_mfma_f32_16x16x32_bf16(a0, w2f[ks][1], acc2[0][1], 0, 0, 0);
      acc2[1][0] = __builtin_amdgcn_mfma_f32_16x16x32_bf16(a1, w2f[ks][0], acc2[1][0], 0, 0, 0);
      acc2[1][1] = __builtin_amdgcn_mfma_f32_16x16x32_bf16(a1, w2f[ks][1], acc2[1][1], 0, 0, 0);
    }
    float m0 = -3.4e38f, m1 = -3.4e38f;
    #pragma unroll
    for (int rt = 0; rt < 2; ++rt)
      #pragma unroll
      for (int reg = 0; reg < 4; ++reg) {
        m0 = fmaxf(m0, acc2[rt][0][reg]);
        m1 = fmaxf(m1, acc2[rt][1][reg]);
      }
    m0 += bias2[0];
    m1 += bias2[1];
    m0 = fmaxf(m0, __shfl_xor(m0, 16));
    m0 = fmaxf(m0, __shfl_xor(m0, 32));
    m1 = fmaxf(m1, __shfl_xor(m1, 16));
    m1 = fmaxf(m1, __shfl_xor(m1, 32));
    if (lane < 16) {
      out[(size_t)(bs0 + q) * CPATCH + 32 * w + lane]      = m0;
      out[(size_t)(bs0 + q) * CPATCH + 32 * w + 16 + lane] = m1;
    }
    __syncthreads();                           // Hs reuse next patch
  }
}

extern "C" void kernel_launch(void* const* d_in, const int* in_sizes, int n_in,
                              void* d_out, int out_size, void* d_ws, size_t ws_size,
                              hipStream_t stream) {
  const float* xyz = (const float*)d_in[0];
  const float* pf  = (const float*)d_in[1];
  const float* pc  = (const float*)d_in[2];
  const float* w1  = (const float*)d_in[3];
  const float* b1  = (const float*)d_in[4];
  const float* w2  = (const float*)d_in[5];
  const float* b2  = (const float*)d_in[6];

  float* out     = (float*)d_out;
  float* idx_out = out + (size_t)B_ * S_ * CPATCH;

  unsigned short* w1p = (unsigned short*)d_ws;          // 96*128 bf16
  unsigned short* w2p = w1p + 96 * 128;                 // 128*128 bf16
  unsigned short* agather = w2p + 128 * 128;            // 8192*3072 bf16 = 50MB

  pack_weights<<<14, 256, 0, stream>>>(w1, w2, w1p, w2p);
  ball_gather_kernel<<<B_ * S_ / 4, 256, 0, stream>>>(xyz, pf, pc, agather, idx_out);
  patch_mlp_mfma<<<B_ * S_ / NQ, 256, 0, stream>>>(agather, w1p, b1, w2p, b2, out);
}

// Round 12
// 51.933 us; speedup vs baseline: 1.1674x; 1.1674x over previous
//
#include <hip/hip_runtime.h>
#include <hip/hip_bf16.h>

#define B_ 8
#define N_ 16384
#define S_ 1024
#define K_ 32
#define CSTEM 64
#define CPATCH 128
#define INDIM 91
#define LDH 136     // wave-private Hs row stride (bf16): 272B -> 2-way (free)

typedef __attribute__((ext_vector_type(8))) short short8v;  // 8 bf16 = 4 VGPRs
typedef __attribute__((ext_vector_type(4))) float f32x4;

static __device__ __forceinline__ unsigned short f2bf(float f) {
  union { float f; unsigned int u; } v; v.f = f;
  return (unsigned short)((v.u + 0x7FFFu + ((v.u >> 16) & 1u)) >> 16);  // RNE
}

static __device__ __forceinline__ short8v cvt8(const float4 a, const float4 b) {
  unsigned short v[8];
  v[0] = f2bf(a.x); v[1] = f2bf(a.y); v[2] = f2bf(a.z); v[3] = f2bf(a.w);
  v[4] = f2bf(b.x); v[5] = f2bf(b.y); v[6] = f2bf(b.z); v[7] = f2bf(b.w);
  return *(const short8v*)v;
}

// PE/rel fragment: cols [64+kq, 64+kq+8) of one row (R8/R11-verified numerics).
static __device__ __forceinline__ short8v pe_frag(
    float r0, float r1, float r2, int kq)
{
  unsigned short v[8];
  #pragma unroll
  for (int j = 0; j < 8; ++j) {
    const int c = 64 + kq + j;
    float val;
    if (c < 67) {
      val = (c == 64) ? r0 : ((c == 65) ? r1 : r2);
    } else if (c < 91) {
      const int qq = c - 67, d = qq >> 3, rbit = qq & 7, band = rbit & 3;
      const float rel = (d == 0) ? r0 : ((d == 1) ? r1 : r2);
      const float ang = rel * ((float)(1 << band) * 3.14159265358979323846f);
      val = (rbit < 4) ? __sinf(ang) : __cosf(ang);
    } else {
      val = 0.f;
    }
    v[j] = f2bf(val);
  }
  return *(const short8v*)v;
}

// -------- Kernel 0: pack w1/w2 into MFMA B-fragment order (bf16) --------
__global__ __launch_bounds__(256) void pack_weights(
    const float* __restrict__ w1, const float* __restrict__ w2,
    unsigned short* __restrict__ w1p, unsigned short* __restrict__ w2p)
{
  const int id = blockIdx.x * 256 + threadIdx.x;
  if (id < 3 * 8 * 64) {                       // w1: K padded 91->96 (3 ksteps)
    const int l = id & 63, ct = (id >> 6) & 7, ks = id >> 9;
    const int col = 16 * ct + (l & 15);
    const int kb = 32 * ks + (l >> 4) * 8;
    unsigned short v[8];
    #pragma unroll
    for (int j = 0; j < 8; ++j) {
      const int k = kb + j;
      v[j] = (k < INDIM) ? f2bf(w1[k * CPATCH + col]) : (unsigned short)0;
    }
    *(short8v*)&w1p[(size_t)id * 8] = *(const short8v*)v;
  } else if (id < 3 * 8 * 64 + 4 * 8 * 64) {   // w2: 4 ksteps
    const int id2 = id - 3 * 8 * 64;
    const int l = id2 & 63, ct = (id2 >> 6) & 7, ks = id2 >> 9;
    const int col = 16 * ct + (l & 15);
    const int kb = 32 * ks + (l >> 4) * 8;
    unsigned short v[8];
    #pragma unroll
    for (int j = 0; j < 8; ++j) v[j] = f2bf(w2[(kb + j) * CPATCH + col]);
    *(short8v*)&w2p[(size_t)id2 * 8] = *(const short8v*)v;
  }
}

// component accessor for an unrolled float4 array (IDX must be compile-time)
#define FCOMP(V, IDX) (((IDX) & 3) == 0 ? (V)[(IDX) >> 2].x : \
                       ((IDX) & 3) == 1 ? (V)[(IDX) >> 2].y : \
                       ((IDX) & 3) == 2 ? (V)[(IDX) >> 2].z : (V)[(IDX) >> 2].w)

// -------- Fused, ZERO-BARRIER: one wave = one complete query pipeline -----
// 4 independent waves per block; no __syncthreads anywhere. Each wave:
// ball scan (verified f32-band+f64 math) -> pad -> idx -> A-frags in regs
// (8x 16B pf loads + pe_frag) -> L1 MFMA (w1 frags streamed from L2, 4 col
// chunks) -> relu/bf16 into WAVE-PRIVATE Hs (no barrier: same-wave LDS
// round-trip, lgkmcnt-ordered) -> L2 MFMA -> shfl-max -> out.
__global__ __launch_bounds__(256, 4) void fused_wave(
    const float* __restrict__ xyz, const float* __restrict__ pf,
    const float* __restrict__ pc,
    const unsigned short* __restrict__ w1p, const float* __restrict__ b1,
    const unsigned short* __restrict__ w2p, const float* __restrict__ b2,
    float* __restrict__ idx_out, float* __restrict__ out)
{
  const int lane = threadIdx.x & 63;
  const int w    = threadIdx.x >> 6;
  const int bs   = blockIdx.x * 4 + w;
  const int b    = bs >> 10;                   // S_ = 1024

  __shared__ int   sidx[4][K_];
  __shared__ float sxyz[4][K_][3];
  __shared__ __align__(16) unsigned short Hs[4][K_][LDH];

  const float* __restrict__ xb  = xyz + (size_t)b * N_ * 3;
  const float* __restrict__ pfb = pf  + (size_t)b * N_ * CSTEM;
  const float cx = pc[bs * 3 + 0];
  const float cy = pc[bs * 3 + 1];
  const float cz = pc[bs * 3 + 2];
  const double rr = 0.2 * 0.2;

  // ---- Ball scan: 1024 pts/iter, wave-local, verified math ----
  int found = 0;
  for (int base = 0; base < N_; base += 1024) {
    const int i0 = base + lane * 16;
    float4 v[12];
    #pragma unroll
    for (int t = 0; t < 12; ++t)
      v[t] = *(const float4*)&xb[i0 * 3 + t * 4];

    unsigned mask = 0u;
    #pragma unroll
    for (int p = 0; p < 16; ++p) {
      const float X = FCOMP(v, 3 * p + 0);
      const float Y = FCOMP(v, 3 * p + 1);
      const float Z = FCOMP(v, 3 * p + 2);
      const float dxf = X - cx, dyf = Y - cy, dzf = Z - cz;
      const float d2f = fmaf(dxf, dxf, fmaf(dyf, dyf, dzf * dzf));
      bool in;
      if (fabsf(d2f - 0.04f) <= 1e-5f) {       // rare exact f64 recheck
        const double dx = (double)X - (double)cx;
        const double dy = (double)Y - (double)cy;
        const double dz = (double)Z - (double)cz;
        in = (dx * dx + dy * dy + dz * dz) <= rr;
      } else {
        in = (d2f < 0.04f);
      }
      if (in) mask |= (1u << p);
    }

    const int cnt = __popc(mask);
    int incl = cnt;                            // wave-inclusive prefix
    #pragma unroll
    for (int d = 1; d < 64; d <<= 1) {
      const int t = __shfl_up(incl, d);
      if (lane >= d) incl += t;
    }
    const int tot = __shfl(incl, 63);

    int pos = found + (incl - cnt);
    #pragma unroll
    for (int p = 0; p < 16; ++p) {             // static p: no dyn reg indexing
      if (mask & (1u << p)) {
        if (pos < K_) {
          sidx[w][pos] = i0 + p;
          sxyz[w][pos][0] = FCOMP(v, 3 * p + 0);
          sxyz[w][pos][1] = FCOMP(v, 3 * p + 1);
          sxyz[w][pos][2] = FCOMP(v, 3 * p + 2);
        }
        ++pos;
      }
    }
    found += tot;
    if (found >= K_) break;                    // wave-uniform
  }

  if (lane == 0 && found == 0) {               // none found -> index N-1
    sidx[w][0] = N_ - 1;
    sxyz[w][0][0] = xb[(N_ - 1) * 3 + 0];
    sxyz[w][0][1] = xb[(N_ - 1) * 3 + 1];
    sxyz[w][0][2] = xb[(N_ - 1) * 3 + 2];
  }
  __threadfence_block();

  if (lane < K_) {                             // pad with first found
    const int   fill = sidx[w][0];
    const float fx = sxyz[w][0][0];
    const float fy = sxyz[w][0][1];
    const float fz = sxyz[w][0][2];
    const int v = (lane < found) ? sidx[w][lane] : fill;
    if (lane >= found) {
      sidx[w][lane] = fill;
      sxyz[w][lane][0] = fx;
      sxyz[w][lane][1] = fy;
      sxyz[w][lane][2] = fz;
    }
    idx_out[(size_t)bs * K_ + lane] = (float)v;
  }
  __threadfence_block();

  // ---- A-fragments straight to registers (R8/R11-verified layout) ----
  const int rfr  = lane & 15;
  const int koff = (lane >> 4) * 8;            // 0,8,16,24

  const int r0 = sidx[w][rfr];
  const int r1 = sidx[w][16 + rfr];
  const float4 u00 = *(const float4*)&pfb[(size_t)r0 * CSTEM + koff];
  const float4 u01 = *(const float4*)&pfb[(size_t)r0 * CSTEM + koff + 4];
  const float4 u02 = *(const float4*)&pfb[(size_t)r0 * CSTEM + 32 + koff];
  const float4 u03 = *(const float4*)&pfb[(size_t)r0 * CSTEM + 32 + koff + 4];
  const float4 u10 = *(const float4*)&pfb[(size_t)r1 * CSTEM + koff];
  const float4 u11 = *(const float4*)&pfb[(size_t)r1 * CSTEM + koff + 4];
  const float4 u12 = *(const float4*)&pfb[(size_t)r1 * CSTEM + 32 + koff];
  const float4 u13 = *(const float4*)&pfb[(size_t)r1 * CSTEM + 32 + koff + 4];

  const short8v a0k2 = pe_frag(sxyz[w][rfr][0] - cx,
                               sxyz[w][rfr][1] - cy,
                               sxyz[w][rfr][2] - cz, koff);
  const short8v a1k2 = pe_frag(sxyz[w][16 + rfr][0] - cx,
                               sxyz[w][16 + rfr][1] - cy,
                               sxyz[w][16 + rfr][2] - cz, koff);
  const short8v a0k0 = cvt8(u00, u01), a0k1 = cvt8(u02, u03);
  const short8v a1k0 = cvt8(u10, u11), a1k1 = cvt8(u12, u13);

  // ---- Layer 1: 4 col-chunks of 32; w1 B-frags streamed from L2 ----
  #pragma unroll
  for (int c = 0; c < 4; ++c) {
    const short8v bA0 = *(const short8v*)&w1p[((size_t)(0 * 8 + 2 * c + 0) * 64 + lane) * 8];
    const short8v bA1 = *(const short8v*)&w1p[((size_t)(0 * 8 + 2 * c + 1) * 64 + lane) * 8];
    const short8v bB0 = *(const short8v*)&w1p[((size_t)(1 * 8 + 2 * c + 0) * 64 + lane) * 8];
    const short8v bB1 = *(const short8v*)&w1p[((size_t)(1 * 8 + 2 * c + 1) * 64 + lane) * 8];
    const short8v bC0 = *(const short8v*)&w1p[((size_t)(2 * 8 + 2 * c + 0) * 64 + lane) * 8];
    const short8v bC1 = *(const short8v*)&w1p[((size_t)(2 * 8 + 2 * c + 1) * 64 + lane) * 8];

    f32x4 acc[2][2] = {};
    acc[0][0] = __builtin_amdgcn_mfma_f32_16x16x32_bf16(a0k0, bA0, acc[0][0], 0, 0, 0);
    acc[0][1] = __builtin_amdgcn_mfma_f32_16x16x32_bf16(a0k0, bA1, acc[0][1], 0, 0, 0);
    acc[1][0] = __builtin_amdgcn_mfma_f32_16x16x32_bf16(a1k0, bA0, acc[1][0], 0, 0, 0);
    acc[1][1] = __builtin_amdgcn_mfma_f32_16x16x32_bf16(a1k0, bA1, acc[1][1], 0, 0, 0);
    acc[0][0] = __builtin_amdgcn_mfma_f32_16x16x32_bf16(a0k1, bB0, acc[0][0], 0, 0, 0);
    acc[0][1] = __builtin_amdgcn_mfma_f32_16x16x32_bf16(a0k1, bB1, acc[0][1], 0, 0, 0);
    acc[1][0] = __builtin_amdgcn_mfma_f32_16x16x32_bf16(a1k1, bB0, acc[1][0], 0, 0, 0);
    acc[1][1] = __builtin_amdgcn_mfma_f32_16x16x32_bf16(a1k1, bB1, acc[1][1], 0, 0, 0);
    acc[0][0] = __builtin_amdgcn_mfma_f32_16x16x32_bf16(a0k2, bC0, acc[0][0], 0, 0, 0);
    acc[0][1] = __builtin_amdgcn_mfma_f32_16x16x32_bf16(a0k2, bC1, acc[0][1], 0, 0, 0);
    acc[1][0] = __builtin_amdgcn_mfma_f32_16x16x32_bf16(a1k2, bC0, acc[1][0], 0, 0, 0);
    acc[1][1] = __builtin_amdgcn_mfma_f32_16x16x32_bf16(a1k2, bC1, acc[1][1], 0, 0, 0);

    const float bia0 = b1[32 * c + rfr];
    const float bia1 = b1[32 * c + 16 + rfr];
    #pragma unroll
    for (int rt = 0; rt < 2; ++rt)
      #pragma unroll
      for (int reg = 0; reg < 4; ++reg) {
        const int row = 16 * rt + (lane >> 4) * 4 + reg;
        Hs[w][row][32 * c + rfr]      = f2bf(fmaxf(acc[rt][0][reg] + bia0, 0.f));
        Hs[w][row][32 * c + 16 + rfr] = f2bf(fmaxf(acc[rt][1][reg] + bia1, 0.f));
      }
  }
  // same-wave LDS round-trip: compiler orders via lgkmcnt, no barrier needed

  // ---- Layer 2 A-frags from wave-private Hs ----
  short8v hf[8];
  #pragma unroll
  for (int ks = 0; ks < 4; ++ks) {
    hf[ks * 2 + 0] = *(const short8v*)&Hs[w][rfr][ks * 32 + koff];
    hf[ks * 2 + 1] = *(const short8v*)&Hs[w][16 + rfr][ks * 32 + koff];
  }

  // ---- Layer 2 + column max, 4 col-chunks; w2 frags streamed ----
  #pragma unroll
  for (int c = 0; c < 4; ++c) {
    f32x4 acc2[2][2] = {};
    #pragma unroll
    for (int ks = 0; ks < 4; ++ks) {
      const short8v b0 = *(const short8v*)&w2p[((size_t)(ks * 8 + 2 * c + 0) * 64 + lane) * 8];
      const short8v b1v = *(const short8v*)&w2p[((size_t)(ks * 8 + 2 * c + 1) * 64 + lane) * 8];
      acc2[0][0] = __builtin_amdgcn_mfma_f32_16x16x32_bf16(hf[ks * 2 + 0], b0,  acc2[0][0], 0, 0, 0);
      acc2[0][1] = __builtin_amdgcn_mfma_f32_16x16x32_bf16(hf[ks * 2 + 0], b1v, acc2[0][1], 0, 0, 0);
      acc2[1][0] = __builtin_amdgcn_mfma_f32_16x16x32_bf16(hf[ks * 2 + 1], b0,  acc2[1][0], 0, 0, 0);
      acc2[1][1] = __builtin_amdgcn_mfma_f32_16x16x32_bf16(hf[ks * 2 + 1], b1v, acc2[1][1], 0, 0, 0);
    }
    float m0 = -3.4e38f, m1 = -3.4e38f;
    #pragma unroll
    for (int rt = 0; rt < 2; ++rt)
      #pragma unroll
      for (int reg = 0; reg < 4; ++reg) {
        m0 = fmaxf(m0, acc2[rt][0][reg]);
        m1 = fmaxf(m1, acc2[rt][1][reg]);
      }
    m0 += b2[32 * c + rfr];
    m1 += b2[32 * c + 16 + rfr];
    m0 = fmaxf(m0, __shfl_xor(m0, 16));
    m0 = fmaxf(m0, __shfl_xor(m0, 32));
    m1 = fmaxf(m1, __shfl_xor(m1, 16));
    m1 = fmaxf(m1, __shfl_xor(m1, 32));
    if (lane < 16) {
      out[(size_t)bs * CPATCH + 32 * c + lane]      = m0;
      out[(size_t)bs * CPATCH + 32 * c + 16 + lane] = m1;
    }
  }
}

extern "C" void kernel_launch(void* const* d_in, const int* in_sizes, int n_in,
                              void* d_out, int out_size, void* d_ws, size_t ws_size,
                              hipStream_t stream) {
  const float* xyz = (const float*)d_in[0];
  const float* pf  = (const float*)d_in[1];
  const float* pc  = (const float*)d_in[2];
  const float* w1  = (const float*)d_in[3];
  const float* b1  = (const float*)d_in[4];
  const float* w2  = (const float*)d_in[5];
  const float* b2  = (const float*)d_in[6];

  float* out     = (float*)d_out;
  float* idx_out = out + (size_t)B_ * S_ * CPATCH;

  unsigned short* w1p = (unsigned short*)d_ws;          // 96*128 bf16
  unsigned short* w2p = w1p + 96 * 128;                 // 128*128 bf16

  pack_weights<<<14, 256, 0, stream>>>(w1, w2, w1p, w2p);
  fused_wave<<<B_ * S_ / 4, 256, 0, stream>>>(xyz, pf, pc, w1p, b1, w2p, b2,
                                              idx_out, out);
}

// Round 13
// 51.571 us; speedup vs baseline: 1.1757x; 1.0070x over previous
//
#include <hip/hip_runtime.h>
#include <hip/hip_bf16.h>

#define B_ 8
#define N_ 16384
#define S_ 1024
#define K_ 32
#define CSTEM 64
#define CPATCH 128
#define INDIM 91
#define LDH 136     // Hs row stride (bf16): 272B -> 2-way (free)

typedef __attribute__((ext_vector_type(8))) short short8v;  // 8 bf16 = 4 VGPRs
typedef __attribute__((ext_vector_type(4))) float f32x4;

static __device__ __forceinline__ unsigned short f2bf(float f) {
  union { float f; unsigned int u; } v; v.f = f;
  return (unsigned short)((v.u + 0x7FFFu + ((v.u >> 16) & 1u)) >> 16);  // RNE
}

static __device__ __forceinline__ short8v cvt8(const float4 a, const float4 b) {
  unsigned short v[8];
  v[0] = f2bf(a.x); v[1] = f2bf(a.y); v[2] = f2bf(a.z); v[3] = f2bf(a.w);
  v[4] = f2bf(b.x); v[5] = f2bf(b.y); v[6] = f2bf(b.z); v[7] = f2bf(b.w);
  return *(const short8v*)v;
}

// PE/rel fragment: cols [64+kq, 64+kq+8) of one row (R8/R11/R12-verified).
static __device__ __forceinline__ short8v pe_frag(
    float r0, float r1, float r2, int kq)
{
  unsigned short v[8];
  #pragma unroll
  for (int j = 0; j < 8; ++j) {
    const int c = 64 + kq + j;
    float val;
    if (c < 67) {
      val = (c == 64) ? r0 : ((c == 65) ? r1 : r2);
    } else if (c < 91) {
      const int qq = c - 67, d = qq >> 3, rbit = qq & 7, band = rbit & 3;
      const float rel = (d == 0) ? r0 : ((d == 1) ? r1 : r2);
      const float ang = rel * ((float)(1 << band) * 3.14159265358979323846f);
      val = (rbit < 4) ? __sinf(ang) : __cosf(ang);
    } else {
      val = 0.f;
    }
    v[j] = f2bf(val);
  }
  return *(const short8v*)v;
}

// -------- Kernel 0: pack w1/w2 into MFMA B-fragment order (bf16) --------
__global__ __launch_bounds__(256) void pack_weights(
    const float* __restrict__ w1, const float* __restrict__ w2,
    unsigned short* __restrict__ w1p, unsigned short* __restrict__ w2p)
{
  const int id = blockIdx.x * 256 + threadIdx.x;
  if (id < 3 * 8 * 64) {                       // w1: K padded 91->96 (3 ksteps)
    const int l = id & 63, ct = (id >> 6) & 7, ks = id >> 9;
    const int col = 16 * ct + (l & 15);
    const int kb = 32 * ks + (l >> 4) * 8;
    unsigned short v[8];
    #pragma unroll
    for (int j = 0; j < 8; ++j) {
      const int k = kb + j;
      v[j] = (k < INDIM) ? f2bf(w1[k * CPATCH + col]) : (unsigned short)0;
    }
    *(short8v*)&w1p[(size_t)id * 8] = *(const short8v*)v;
  } else if (id < 3 * 8 * 64 + 4 * 8 * 64) {   // w2: 4 ksteps
    const int id2 = id - 3 * 8 * 64;
    const int l = id2 & 63, ct = (id2 >> 6) & 7, ks = id2 >> 9;
    const int col = 16 * ct + (l & 15);
    const int kb = 32 * ks + (l >> 4) * 8;
    unsigned short v[8];
    #pragma unroll
    for (int j = 0; j < 8; ++j) v[j] = f2bf(w2[(kb + j) * CPATCH + col]);
    *(short8v*)&w2p[(size_t)id2 * 8] = *(const short8v*)v;
  }
}

// component accessor for an unrolled float4 array (IDX must be compile-time)
#define FCOMP(V, IDX) (((IDX) & 3) == 0 ? (V)[(IDX) >> 2].x : \
                       ((IDX) & 3) == 1 ? (V)[(IDX) >> 2].y : \
                       ((IDX) & 3) == 2 ? (V)[(IDX) >> 2].z : (V)[(IDX) >> 2].w)

// -------- Fused, one wave = one query = one 64-thread block ---------------
// Per-wave pipeline identical to R12 (verified numerics throughout); block
// size 64 so each finished query immediately frees its CU slot (fine-grain
// dynamic load balancing; stragglers no longer hold sibling waves).
__global__ __launch_bounds__(64, 4) void fused_wave(
    const float* __restrict__ xyz, const float* __restrict__ pf,
    const float* __restrict__ pc,
    const unsigned short* __restrict__ w1p, const float* __restrict__ b1,
    const unsigned short* __restrict__ w2p, const float* __restrict__ b2,
    float* __restrict__ idx_out, float* __restrict__ out)
{
  const int lane = threadIdx.x;                // 0..63
  const int bs   = blockIdx.x;
  const int b    = bs >> 10;                   // S_ = 1024

  __shared__ int   sidx[K_];
  __shared__ float sxyz[K_][3];
  __shared__ __align__(16) unsigned short Hs[K_][LDH];

  const float* __restrict__ xb  = xyz + (size_t)b * N_ * 3;
  const float* __restrict__ pfb = pf  + (size_t)b * N_ * CSTEM;
  const float cx = pc[bs * 3 + 0];
  const float cy = pc[bs * 3 + 1];
  const float cz = pc[bs * 3 + 2];
  const double rr = 0.2 * 0.2;

  // ---- Ball scan: 1024 pts/iter, wave-local, verified math ----
  int found = 0;
  for (int base = 0; base < N_; base += 1024) {
    const int i0 = base + lane * 16;
    float4 v[12];
    #pragma unroll
    for (int t = 0; t < 12; ++t)
      v[t] = *(const float4*)&xb[i0 * 3 + t * 4];

    unsigned mask = 0u;
    #pragma unroll
    for (int p = 0; p < 16; ++p) {
      const float X = FCOMP(v, 3 * p + 0);
      const float Y = FCOMP(v, 3 * p + 1);
      const float Z = FCOMP(v, 3 * p + 2);
      const float dxf = X - cx, dyf = Y - cy, dzf = Z - cz;
      const float d2f = fmaf(dxf, dxf, fmaf(dyf, dyf, dzf * dzf));
      bool in;
      if (fabsf(d2f - 0.04f) <= 1e-5f) {       // rare exact f64 recheck
        const double dx = (double)X - (double)cx;
        const double dy = (double)Y - (double)cy;
        const double dz = (double)Z - (double)cz;
        in = (dx * dx + dy * dy + dz * dz) <= rr;
      } else {
        in = (d2f < 0.04f);
      }
      if (in) mask |= (1u << p);
    }

    const int cnt = __popc(mask);
    int incl = cnt;                            // wave-inclusive prefix
    #pragma unroll
    for (int d = 1; d < 64; d <<= 1) {
      const int t = __shfl_up(incl, d);
      if (lane >= d) incl += t;
    }
    const int tot = __shfl(incl, 63);

    int pos = found + (incl - cnt);
    #pragma unroll
    for (int p = 0; p < 16; ++p) {             // static p: no dyn reg indexing
      if (mask & (1u << p)) {
        if (pos < K_) {
          sidx[pos] = i0 + p;
          sxyz[pos][0] = FCOMP(v, 3 * p + 0);
          sxyz[pos][1] = FCOMP(v, 3 * p + 1);
          sxyz[pos][2] = FCOMP(v, 3 * p + 2);
        }
        ++pos;
      }
    }
    found += tot;
    if (found >= K_) break;                    // wave-uniform
  }

  if (lane == 0 && found == 0) {               // none found -> index N-1
    sidx[0] = N_ - 1;
    sxyz[0][0] = xb[(N_ - 1) * 3 + 0];
    sxyz[0][1] = xb[(N_ - 1) * 3 + 1];
    sxyz[0][2] = xb[(N_ - 1) * 3 + 2];
  }
  __threadfence_block();

  if (lane < K_) {                             // pad with first found
    const int   fill = sidx[0];
    const float fx = sxyz[0][0];
    const float fy = sxyz[0][1];
    const float fz = sxyz[0][2];
    const int v = (lane < found) ? sidx[lane] : fill;
    if (lane >= found) {
      sidx[lane] = fill;
      sxyz[lane][0] = fx;
      sxyz[lane][1] = fy;
      sxyz[lane][2] = fz;
    }
    idx_out[(size_t)bs * K_ + lane] = (float)v;
  }
  __threadfence_block();

  // ---- A-fragments straight to registers (verified layout) ----
  const int rfr  = lane & 15;
  const int koff = (lane >> 4) * 8;            // 0,8,16,24

  const int r0 = sidx[rfr];
  const int r1 = sidx[16 + rfr];
  const float4 u00 = *(const float4*)&pfb[(size_t)r0 * CSTEM + koff];
  const float4 u01 = *(const float4*)&pfb[(size_t)r0 * CSTEM + koff + 4];
  const float4 u02 = *(const float4*)&pfb[(size_t)r0 * CSTEM + 32 + koff];
  const float4 u03 = *(const float4*)&pfb[(size_t)r0 * CSTEM + 32 + koff + 4];
  const float4 u10 = *(const float4*)&pfb[(size_t)r1 * CSTEM + koff];
  const float4 u11 = *(const float4*)&pfb[(size_t)r1 * CSTEM + koff + 4];
  const float4 u12 = *(const float4*)&pfb[(size_t)r1 * CSTEM + 32 + koff];
  const float4 u13 = *(const float4*)&pfb[(size_t)r1 * CSTEM + 32 + koff + 4];

  const short8v a0k2 = pe_frag(sxyz[rfr][0] - cx,
                               sxyz[rfr][1] - cy,
                               sxyz[rfr][2] - cz, koff);
  const short8v a1k2 = pe_frag(sxyz[16 + rfr][0] - cx,
                               sxyz[16 + rfr][1] - cy,
                               sxyz[16 + rfr][2] - cz, koff);
  const short8v a0k0 = cvt8(u00, u01), a0k1 = cvt8(u02, u03);
  const short8v a1k0 = cvt8(u10, u11), a1k1 = cvt8(u12, u13);

  // ---- Layer 1: 4 col-chunks of 32; w1 B-frags streamed from L2 ----
  #pragma unroll
  for (int c = 0; c < 4; ++c) {
    const short8v bA0 = *(const short8v*)&w1p[((size_t)(0 * 8 + 2 * c + 0) * 64 + lane) * 8];
    const short8v bA1 = *(const short8v*)&w1p[((size_t)(0 * 8 + 2 * c + 1) * 64 + lane) * 8];
    const short8v bB0 = *(const short8v*)&w1p[((size_t)(1 * 8 + 2 * c + 0) * 64 + lane) * 8];
    const short8v bB1 = *(const short8v*)&w1p[((size_t)(1 * 8 + 2 * c + 1) * 64 + lane) * 8];
    const short8v bC0 = *(const short8v*)&w1p[((size_t)(2 * 8 + 2 * c + 0) * 64 + lane) * 8];
    const short8v bC1 = *(const short8v*)&w1p[((size_t)(2 * 8 + 2 * c + 1) * 64 + lane) * 8];

    f32x4 acc[2][2] = {};
    acc[0][0] = __builtin_amdgcn_mfma_f32_16x16x32_bf16(a0k0, bA0, acc[0][0], 0, 0, 0);
    acc[0][1] = __builtin_amdgcn_mfma_f32_16x16x32_bf16(a0k0, bA1, acc[0][1], 0, 0, 0);
    acc[1][0] = __builtin_amdgcn_mfma_f32_16x16x32_bf16(a1k0, bA0, acc[1][0], 0, 0, 0);
    acc[1][1] = __builtin_amdgcn_mfma_f32_16x16x32_bf16(a1k0, bA1, acc[1][1], 0, 0, 0);
    acc[0][0] = __builtin_amdgcn_mfma_f32_16x16x32_bf16(a0k1, bB0, acc[0][0], 0, 0, 0);
    acc[0][1] = __builtin_amdgcn_mfma_f32_16x16x32_bf16(a0k1, bB1, acc[0][1], 0, 0, 0);
    acc[1][0] = __builtin_amdgcn_mfma_f32_16x16x32_bf16(a1k1, bB0, acc[1][0], 0, 0, 0);
    acc[1][1] = __builtin_amdgcn_mfma_f32_16x16x32_bf16(a1k1, bB1, acc[1][1], 0, 0, 0);
    acc[0][0] = __builtin_amdgcn_mfma_f32_16x16x32_bf16(a0k2, bC0, acc[0][0], 0, 0, 0);
    acc[0][1] = __builtin_amdgcn_mfma_f32_16x16x32_bf16(a0k2, bC1, acc[0][1], 0, 0, 0);
    acc[1][0] = __builtin_amdgcn_mfma_f32_16x16x32_bf16(a1k2, bC0, acc[1][0], 0, 0, 0);
    acc[1][1] = __builtin_amdgcn_mfma_f32_16x16x32_bf16(a1k2, bC1, acc[1][1], 0, 0, 0);

    const float bia0 = b1[32 * c + rfr];
    const float bia1 = b1[32 * c + 16 + rfr];
    #pragma unroll
    for (int rt = 0; rt < 2; ++rt)
      #pragma unroll
      for (int reg = 0; reg < 4; ++reg) {
        const int row = 16 * rt + (lane >> 4) * 4 + reg;
        Hs[row][32 * c + rfr]      = f2bf(fmaxf(acc[rt][0][reg] + bia0, 0.f));
        Hs[row][32 * c + 16 + rfr] = f2bf(fmaxf(acc[rt][1][reg] + bia1, 0.f));
      }
  }
  // same-wave LDS round-trip: ordered via lgkmcnt, no barrier needed

  // ---- Layer 2 A-frags from Hs ----
  short8v hf[8];
  #pragma unroll
  for (int ks = 0; ks < 4; ++ks) {
    hf[ks * 2 + 0] = *(const short8v*)&Hs[rfr][ks * 32 + koff];
    hf[ks * 2 + 1] = *(const short8v*)&Hs[16 + rfr][ks * 32 + koff];
  }

  // ---- Layer 2 + column max, 4 col-chunks; w2 frags streamed ----
  #pragma unroll
  for (int c = 0; c < 4; ++c) {
    f32x4 acc2[2][2] = {};
    #pragma unroll
    for (int ks = 0; ks < 4; ++ks) {
      const short8v b0 = *(const short8v*)&w2p[((size_t)(ks * 8 + 2 * c + 0) * 64 + lane) * 8];
      const short8v b1v = *(const short8v*)&w2p[((size_t)(ks * 8 + 2 * c + 1) * 64 + lane) * 8];
      acc2[0][0] = __builtin_amdgcn_mfma_f32_16x16x32_bf16(hf[ks * 2 + 0], b0,  acc2[0][0], 0, 0, 0);
      acc2[0][1] = __builtin_amdgcn_mfma_f32_16x16x32_bf16(hf[ks * 2 + 0], b1v, acc2[0][1], 0, 0, 0);
      acc2[1][0] = __builtin_amdgcn_mfma_f32_16x16x32_bf16(hf[ks * 2 + 1], b0,  acc2[1][0], 0, 0, 0);
      acc2[1][1] = __builtin_amdgcn_mfma_f32_16x16x32_bf16(hf[ks * 2 + 1], b1v, acc2[1][1], 0, 0, 0);
    }
    float m0 = -3.4e38f, m1 = -3.4e38f;
    #pragma unroll
    for (int rt = 0; rt < 2; ++rt)
      #pragma unroll
      for (int reg = 0; reg < 4; ++reg) {
        m0 = fmaxf(m0, acc2[rt][0][reg]);
        m1 = fmaxf(m1, acc2[rt][1][reg]);
      }
    m0 += b2[32 * c + rfr];
    m1 += b2[32 * c + 16 + rfr];
    m0 = fmaxf(m0, __shfl_xor(m0, 16));
    m0 = fmaxf(m0, __shfl_xor(m0, 32));
    m1 = fmaxf(m1, __shfl_xor(m1, 16));
    m1 = fmaxf(m1, __shfl_xor(m1, 32));
    if (lane < 16) {
      out[(size_t)bs * CPATCH + 32 * c + lane]      = m0;
      out[(size_t)bs * CPATCH + 32 * c + 16 + lane] = m1;
    }
  }
}

extern "C" void kernel_launch(void* const* d_in, const int* in_sizes, int n_in,
                              void* d_out, int out_size, void* d_ws, size_t ws_size,
                              hipStream_t stream) {
  const float* xyz = (const float*)d_in[0];
  const float* pf  = (const float*)d_in[1];
  const float* pc  = (const float*)d_in[2];
  const float* w1  = (const float*)d_in[3];
  const float* b1  = (const float*)d_in[4];
  const float* w2  = (const float*)d_in[5];
  const float* b2  = (const float*)d_in[6];

  float* out     = (float*)d_out;
  float* idx_out = out + (size_t)B_ * S_ * CPATCH;

  unsigned short* w1p = (unsigned short*)d_ws;          // 96*128 bf16
  unsigned short* w2p = w1p + 96 * 128;                 // 128*128 bf16

  pack_weights<<<14, 256, 0, stream>>>(w1, w2, w1p, w2p);
  fused_wave<<<B_ * S_, 64, 0, stream>>>(xyz, pf, pc, w1p, b1, w2p, b2,
                                         idx_out, out);
}

// Round 14
// 46.600 us; speedup vs baseline: 1.3010x; 1.1067x over previous
//
#include <hip/hip_runtime.h>
#include <hip/hip_bf16.h>

#define B_ 8
#define N_ 16384
#define S_ 1024
#define K_ 32
#define CSTEM 64
#define CPATCH 128
#define INDIM 91
#define LDH 136     // Hs row stride (bf16): 272B -> 2-way (free)

typedef __attribute__((ext_vector_type(8))) short short8v;  // 8 bf16 = 4 VGPRs
typedef __attribute__((ext_vector_type(4))) float f32x4;

static __device__ __forceinline__ unsigned short f2bf(float f) {
  union { float f; unsigned int u; } v; v.f = f;
  return (unsigned short)((v.u + 0x7FFFu + ((v.u >> 16) & 1u)) >> 16);  // RNE
}

static __device__ __forceinline__ short8v cvt8(const float4 a, const float4 b) {
  unsigned short v[8];
  v[0] = f2bf(a.x); v[1] = f2bf(a.y); v[2] = f2bf(a.z); v[3] = f2bf(a.w);
  v[4] = f2bf(b.x); v[5] = f2bf(b.y); v[6] = f2bf(b.z); v[7] = f2bf(b.w);
  return *(const short8v*)v;
}

// PE/rel fragment: cols [64+kq, 64+kq+8) of one row (R8/R11/R12/R13-verified).
static __device__ __forceinline__ short8v pe_frag(
    float r0, float r1, float r2, int kq)
{
  unsigned short v[8];
  #pragma unroll
  for (int j = 0; j < 8; ++j) {
    const int c = 64 + kq + j;
    float val;
    if (c < 67) {
      val = (c == 64) ? r0 : ((c == 65) ? r1 : r2);
    } else if (c < 91) {
      const int qq = c - 67, d = qq >> 3, rbit = qq & 7, band = rbit & 3;
      const float rel = (d == 0) ? r0 : ((d == 1) ? r1 : r2);
      const float ang = rel * ((float)(1 << band) * 3.14159265358979323846f);
      val = (rbit < 4) ? __sinf(ang) : __cosf(ang);
    } else {
      val = 0.f;
    }
    v[j] = f2bf(val);
  }
  return *(const short8v*)v;
}

// -------- Kernel 0: pack w1/w2 into MFMA B-fragment order (bf16) --------
__global__ __launch_bounds__(256) void pack_weights(
    const float* __restrict__ w1, const float* __restrict__ w2,
    unsigned short* __restrict__ w1p, unsigned short* __restrict__ w2p)
{
  const int id = blockIdx.x * 256 + threadIdx.x;
  if (id < 3 * 8 * 64) {                       // w1: K padded 91->96 (3 ksteps)
    const int l = id & 63, ct = (id >> 6) & 7, ks = id >> 9;
    const int col = 16 * ct + (l & 15);
    const int kb = 32 * ks + (l >> 4) * 8;
    unsigned short v[8];
    #pragma unroll
    for (int j = 0; j < 8; ++j) {
      const int k = kb + j;
      v[j] = (k < INDIM) ? f2bf(w1[k * CPATCH + col]) : (unsigned short)0;
    }
    *(short8v*)&w1p[(size_t)id * 8] = *(const short8v*)v;
  } else if (id < 3 * 8 * 64 + 4 * 8 * 64) {   // w2: 4 ksteps
    const int id2 = id - 3 * 8 * 64;
    const int l = id2 & 63, ct = (id2 >> 6) & 7, ks = id2 >> 9;
    const int col = 16 * ct + (l & 15);
    const int kb = 32 * ks + (l >> 4) * 8;
    unsigned short v[8];
    #pragma unroll
    for (int j = 0; j < 8; ++j) v[j] = f2bf(w2[(kb + j) * CPATCH + col]);
    *(short8v*)&w2p[(size_t)id2 * 8] = *(const short8v*)v;
  }
}

// test 4 consecutive points packed in 3 float4 (R3/R7-verified component map)
// against center (cx,cy,cz); f32 fast path + f64 recheck band (verified).
#define TEST4(V0, V1, V2, MASKVAR) do {                                    \
    MASKVAR = 0u;                                                          \
    const float X[4] = {(V0).x, (V0).w, (V1).z, (V2).y};                   \
    const float Y[4] = {(V0).y, (V1).x, (V1).w, (V2).z};                   \
    const float Z[4] = {(V0).z, (V1).y, (V2).x, (V2).w};                   \
    _Pragma("unroll")                                                      \
    for (int p = 0; p < 4; ++p) {                                          \
      const float dxf = X[p] - cx, dyf = Y[p] - cy, dzf = Z[p] - cz;       \
      const float d2f = fmaf(dxf, dxf, fmaf(dyf, dyf, dzf * dzf));         \
      bool in;                                                             \
      if (fabsf(d2f - 0.04f) <= 1e-5f) {                                   \
        const double dx = (double)X[p] - (double)cx;                       \
        const double dy = (double)Y[p] - (double)cy;                       \
        const double dz = (double)Z[p] - (double)cz;                       \
        in = (dx * dx + dy * dy + dz * dz) <= (0.2 * 0.2);                 \
      } else {                                                             \
        in = (d2f < 0.04f);                                                \
      }                                                                    \
      if (in) MASKVAR |= (1u << p);                                        \
    }                                                                      \
  } while (0)

// append one sub-chunk's up-to-4 hits (static unroll; coords from V regs)
#define APPEND4(MASKVAR, POSVAR, I0, V0, V1, V2) do {                      \
    if ((MASKVAR) & 1u) { if ((POSVAR) < K_) { sidx[POSVAR] = (I0) + 0;    \
      sxyz[POSVAR][0] = (V0).x; sxyz[POSVAR][1] = (V0).y;                  \
      sxyz[POSVAR][2] = (V0).z; } ++(POSVAR); }                            \
    if ((MASKVAR) & 2u) { if ((POSVAR) < K_) { sidx[POSVAR] = (I0) + 1;    \
      sxyz[POSVAR][0] = (V0).w; sxyz[POSVAR][1] = (V1).x;                  \
      sxyz[POSVAR][2] = (V1).y; } ++(POSVAR); }                            \
    if ((MASKVAR) & 4u) { if ((POSVAR) < K_) { sidx[POSVAR] = (I0) + 2;    \
      sxyz[POSVAR][0] = (V1).z; sxyz[POSVAR][1] = (V1).w;                  \
      sxyz[POSVAR][2] = (V2).x; } ++(POSVAR); }                            \
    if ((MASKVAR) & 8u) { if ((POSVAR) < K_) { sidx[POSVAR] = (I0) + 3;    \
      sxyz[POSVAR][0] = (V2).y; sxyz[POSVAR][1] = (V2).z;                  \
      sxyz[POSVAR][2] = (V2).w; } ++(POSVAR); }                            \
  } while (0)

// -------- Fused, one wave = one query = one 64-thread block ---------------
// Ball loop reworked vs R13: 512-pt chunks, lane owns 2x4 CONSECUTIVE points
// (48B lane stride -> ~24 cache lines/instr vs 64 at 192B stride) and the
// next chunk is register-prefetched so VMEM latency hides under the tests.
// All math bit-identical to verified versions. MLP phase verbatim R13.
__global__ __launch_bounds__(64, 4) void fused_wave(
    const float* __restrict__ xyz, const float* __restrict__ pf,
    const float* __restrict__ pc,
    const unsigned short* __restrict__ w1p, const float* __restrict__ b1,
    const unsigned short* __restrict__ w2p, const float* __restrict__ b2,
    float* __restrict__ idx_out, float* __restrict__ out)
{
  const int lane = threadIdx.x;                // 0..63
  const int bs   = blockIdx.x;
  const int b    = bs >> 10;                   // S_ = 1024

  __shared__ int   sidx[K_];
  __shared__ float sxyz[K_][3];
  __shared__ __align__(16) unsigned short Hs[K_][LDH];

  const float* __restrict__ xb  = xyz + (size_t)b * N_ * 3;
  const float* __restrict__ pfb = pf  + (size_t)b * N_ * CSTEM;
  const float cx = pc[bs * 3 + 0];
  const float cy = pc[bs * 3 + 1];
  const float cz = pc[bs * 3 + 2];

  // ---- Ball scan: 512-pt chunks (2 subs x 4 pts/lane), prefetched ----
  int found = 0;
  {
    const int lo3 = lane * 12;                 // (lane*4)*3 floats
    int base = 0;
    float4 v0 = *(const float4*)&xb[lo3 + 0];
    float4 v1 = *(const float4*)&xb[lo3 + 4];
    float4 v2 = *(const float4*)&xb[lo3 + 8];
    float4 v3 = *(const float4*)&xb[256 * 3 + lo3 + 0];
    float4 v4 = *(const float4*)&xb[256 * 3 + lo3 + 4];
    float4 v5 = *(const float4*)&xb[256 * 3 + lo3 + 8];

    for (;;) {
      const int nb = (base + 512 < N_) ? base + 512 : base;  // clamped prefetch
      const float4 n0 = *(const float4*)&xb[nb * 3 + lo3 + 0];
      const float4 n1 = *(const float4*)&xb[nb * 3 + lo3 + 4];
      const float4 n2 = *(const float4*)&xb[nb * 3 + lo3 + 8];
      const float4 n3 = *(const float4*)&xb[(nb + 256) * 3 + lo3 + 0];
      const float4 n4 = *(const float4*)&xb[(nb + 256) * 3 + lo3 + 4];
      const float4 n5 = *(const float4*)&xb[(nb + 256) * 3 + lo3 + 8];

      unsigned m0, m1;
      TEST4(v0, v1, v2, m0);                   // sub 0: pts base+lane*4..+3
      TEST4(v3, v4, v5, m1);                   // sub 1: pts base+256+lane*4..+3

      const int c0 = __popc(m0), c1 = __popc(m1);
      unsigned incl = (unsigned)c0 | ((unsigned)c1 << 16);
      #pragma unroll
      for (int d = 1; d < 64; d <<= 1) {       // packed dual prefix (no ovfl)
        const unsigned t = (unsigned)__shfl_up((int)incl, d);
        if (lane >= d) incl += t;
      }
      const unsigned tot = (unsigned)__shfl((int)incl, 63);
      const int t0 = (int)(tot & 0xFFFFu), t1 = (int)(tot >> 16);

      int pos0 = found + (int)((incl & 0xFFFFu)) - c0;
      int pos1 = found + t0 + (int)(incl >> 16) - c1;
      const int i0 = base + lane * 4;
      APPEND4(m0, pos0, i0, v0, v1, v2);
      APPEND4(m1, pos1, i0 + 256, v3, v4, v5);

      found += t0 + t1;
      if (found >= K_) break;                  // wave-uniform
      base += 512;
      if (base >= N_) break;
      v0 = n0; v1 = n1; v2 = n2; v3 = n3; v4 = n4; v5 = n5;
    }
  }

  if (lane == 0 && found == 0) {               // none found -> index N-1
    sidx[0] = N_ - 1;
    sxyz[0][0] = xb[(N_ - 1) * 3 + 0];
    sxyz[0][1] = xb[(N_ - 1) * 3 + 1];
    sxyz[0][2] = xb[(N_ - 1) * 3 + 2];
  }
  __threadfence_block();

  if (lane < K_) {                             // pad with first found
    const int   fill = sidx[0];
    const float fx = sxyz[0][0];
    const float fy = sxyz[0][1];
    const float fz = sxyz[0][2];
    const int v = (lane < found) ? sidx[lane] : fill;
    if (lane >= found) {
      sidx[lane] = fill;
      sxyz[lane][0] = fx;
      sxyz[lane][1] = fy;
      sxyz[lane][2] = fz;
    }
    idx_out[(size_t)bs * K_ + lane] = (float)v;
  }
  __threadfence_block();

  // ---- A-fragments straight to registers (verified layout, verbatim R13) --
  const int rfr  = lane & 15;
  const int koff = (lane >> 4) * 8;            // 0,8,16,24

  const int r0 = sidx[rfr];
  const int r1 = sidx[16 + rfr];
  const float4 u00 = *(const float4*)&pfb[(size_t)r0 * CSTEM + koff];
  const float4 u01 = *(const float4*)&pfb[(size_t)r0 * CSTEM + koff + 4];
  const float4 u02 = *(const float4*)&pfb[(size_t)r0 * CSTEM + 32 + koff];
  const float4 u03 = *(const float4*)&pfb[(size_t)r0 * CSTEM + 32 + koff + 4];
  const float4 u10 = *(const float4*)&pfb[(size_t)r1 * CSTEM + koff];
  const float4 u11 = *(const float4*)&pfb[(size_t)r1 * CSTEM + koff + 4];
  const float4 u12 = *(const float4*)&pfb[(size_t)r1 * CSTEM + 32 + koff];
  const float4 u13 = *(const float4*)&pfb[(size_t)r1 * CSTEM + 32 + koff + 4];

  const short8v a0k2 = pe_frag(sxyz[rfr][0] - cx,
                               sxyz[rfr][1] - cy,
                               sxyz[rfr][2] - cz, koff);
  const short8v a1k2 = pe_frag(sxyz[16 + rfr][0] - cx,
                               sxyz[16 + rfr][1] - cy,
                               sxyz[16 + rfr][2] - cz, koff);
  const short8v a0k0 = cvt8(u00, u01), a0k1 = cvt8(u02, u03);
  const short8v a1k0 = cvt8(u10, u11), a1k1 = cvt8(u12, u13);

  // ---- Layer 1: 4 col-chunks of 32; w1 B-frags streamed from L2 ----
  #pragma unroll
  for (int c = 0; c < 4; ++c) {
    const short8v bA0 = *(const short8v*)&w1p[((size_t)(0 * 8 + 2 * c + 0) * 64 + lane) * 8];
    const short8v bA1 = *(const short8v*)&w1p[((size_t)(0 * 8 + 2 * c + 1) * 64 + lane) * 8];
    const short8v bB0 = *(const short8v*)&w1p[((size_t)(1 * 8 + 2 * c + 0) * 64 + lane) * 8];
    const short8v bB1 = *(const short8v*)&w1p[((size_t)(1 * 8 + 2 * c + 1) * 64 + lane) * 8];
    const short8v bC0 = *(const short8v*)&w1p[((size_t)(2 * 8 + 2 * c + 0) * 64 + lane) * 8];
    const short8v bC1 = *(const short8v*)&w1p[((size_t)(2 * 8 + 2 * c + 1) * 64 + lane) * 8];

    f32x4 acc[2][2] = {};
    acc[0][0] = __builtin_amdgcn_mfma_f32_16x16x32_bf16(a0k0, bA0, acc[0][0], 0, 0, 0);
    acc[0][1] = __builtin_amdgcn_mfma_f32_16x16x32_bf16(a0k0, bA1, acc[0][1], 0, 0, 0);
    acc[1][0] = __builtin_amdgcn_mfma_f32_16x16x32_bf16(a1k0, bA0, acc[1][0], 0, 0, 0);
    acc[1][1] = __builtin_amdgcn_mfma_f32_16x16x32_bf16(a1k0, bA1, acc[1][1], 0, 0, 0);
    acc[0][0] = __builtin_amdgcn_mfma_f32_16x16x32_bf16(a0k1, bB0, acc[0][0], 0, 0, 0);
    acc[0][1] = __builtin_amdgcn_mfma_f32_16x16x32_bf16(a0k1, bB1, acc[0][1], 0, 0, 0);
    acc[1][0] = __builtin_amdgcn_mfma_f32_16x16x32_bf16(a1k1, bB0, acc[1][0], 0, 0, 0);
    acc[1][1] = __builtin_amdgcn_mfma_f32_16x16x32_bf16(a1k1, bB1, acc[1][1], 0, 0, 0);
    acc[0][0] = __builtin_amdgcn_mfma_f32_16x16x32_bf16(a0k2, bC0, acc[0][0], 0, 0, 0);
    acc[0][1] = __builtin_amdgcn_mfma_f32_16x16x32_bf16(a0k2, bC1, acc[0][1], 0, 0, 0);
    acc[1][0] = __builtin_amdgcn_mfma_f32_16x16x32_bf16(a1k2, bC0, acc[1][0], 0, 0, 0);
    acc[1][1] = __builtin_amdgcn_mfma_f32_16x16x32_bf16(a1k2, bC1, acc[1][1], 0, 0, 0);

    const float bia0 = b1[32 * c + rfr];
    const float bia1 = b1[32 * c + 16 + rfr];
    #pragma unroll
    for (int rt = 0; rt < 2; ++rt)
      #pragma unroll
      for (int reg = 0; reg < 4; ++reg) {
        const int row = 16 * rt + (lane >> 4) * 4 + reg;
        Hs[row][32 * c + rfr]      = f2bf(fmaxf(acc[rt][0][reg] + bia0, 0.f));
        Hs[row][32 * c + 16 + rfr] = f2bf(fmaxf(acc[rt][1][reg] + bia1, 0.f));
      }
  }
  // same-wave LDS round-trip: ordered via lgkmcnt, no barrier needed

  // ---- Layer 2 A-frags from Hs ----
  short8v hf[8];
  #pragma unroll
  for (int ks = 0; ks < 4; ++ks) {
    hf[ks * 2 + 0] = *(const short8v*)&Hs[rfr][ks * 32 + koff];
    hf[ks * 2 + 1] = *(const short8v*)&Hs[16 + rfr][ks * 32 + koff];
  }

  // ---- Layer 2 + column max, 4 col-chunks; w2 frags streamed ----
  #pragma unroll
  for (int c = 0; c < 4; ++c) {
    f32x4 acc2[2][2] = {};
    #pragma unroll
    for (int ks = 0; ks < 4; ++ks) {
      const short8v b0 = *(const short8v*)&w2p[((size_t)(ks * 8 + 2 * c + 0) * 64 + lane) * 8];
      const short8v b1v = *(const short8v*)&w2p[((size_t)(ks * 8 + 2 * c + 1) * 64 + lane) * 8];
      acc2[0][0] = __builtin_amdgcn_mfma_f32_16x16x32_bf16(hf[ks * 2 + 0], b0,  acc2[0][0], 0, 0, 0);
      acc2[0][1] = __builtin_amdgcn_mfma_f32_16x16x32_bf16(hf[ks * 2 + 0], b1v, acc2[0][1], 0, 0, 0);
      acc2[1][0] = __builtin_amdgcn_mfma_f32_16x16x32_bf16(hf[ks * 2 + 1], b0,  acc2[1][0], 0, 0, 0);
      acc2[1][1] = __builtin_amdgcn_mfma_f32_16x16x32_bf16(hf[ks * 2 + 1], b1v, acc2[1][1], 0, 0, 0);
    }
    float m0 = -3.4e38f, m1 = -3.4e38f;
    #pragma unroll
    for (int rt = 0; rt < 2; ++rt)
      #pragma unroll
      for (int reg = 0; reg < 4; ++reg) {
        m0 = fmaxf(m0, acc2[rt][0][reg]);
        m1 = fmaxf(m1, acc2[rt][1][reg]);
      }
    m0 += b2[32 * c + rfr];
    m1 += b2[32 * c + 16 + rfr];
    m0 = fmaxf(m0, __shfl_xor(m0, 16));
    m0 = fmaxf(m0, __shfl_xor(m0, 32));
    m1 = fmaxf(m1, __shfl_xor(m1, 16));
    m1 = fmaxf(m1, __shfl_xor(m1, 32));
    if (lane < 16) {
      out[(size_t)bs * CPATCH + 32 * c + lane]      = m0;
      out[(size_t)bs * CPATCH + 32 * c + 16 + lane] = m1;
    }
  }
}

extern "C" void kernel_launch(void* const* d_in, const int* in_sizes, int n_in,
                              void* d_out, int out_size, void* d_ws, size_t ws_size,
                              hipStream_t stream) {
  const float* xyz = (const float*)d_in[0];
  const float* pf  = (const float*)d_in[1];
  const float* pc  = (const float*)d_in[2];
  const float* w1  = (const float*)d_in[3];
  const float* b1  = (const float*)d_in[4];
  const float* w2  = (const float*)d_in[5];
  const float* b2  = (const float*)d_in[6];

  float* out     = (float*)d_out;
  float* idx_out = out + (size_t)B_ * S_ * CPATCH;

  unsigned short* w1p = (unsigned short*)d_ws;          // 96*128 bf16
  unsigned short* w2p = w1p + 96 * 128;                 // 128*128 bf16

  pack_weights<<<14, 256, 0, stream>>>(w1, w2, w1p, w2p);
  fused_wave<<<B_ * S_, 64, 0, stream>>>(xyz, pf, pc, w1p, b1, w2p, b2,
                                         idx_out, out);
}